// Round 7
// baseline (143.527 us; speedup 1.0000x reference)
//
#include <hip/hip_runtime.h>

// Pipeline_8400956031319: dual greedy NMS (8192 det + 8192 rpn, IOU>0.6,
// index order) + argmax masking.
//
// R6 structure (sparse + spatially binned):
//   Kernel 1 (bin):   per set, bin boxes by center into a 16x16 grid of
//                     128px cells (max box size 120 < 128 => only 3x3
//                     neighborhoods can overlap), LDS histogram + scan,
//                     scatter sorted box/area/idx arrays; zero edge counter.
//   Kernel 2 (pair):  per (cell,set) block: test cell boxes against 3x3
//                     neighborhood (3 contiguous runs), exact ref IOU on
//                     inter>0 pairs, emit packed edges (i<<13|j, i<j orig).
//                     ~2.4M pair tests/set vs 16.8M dense (R6 was 46us).
//   Kernel 3 (solve): Jacobi fixpoint of keep[j] = !(exists i<j edge, keep[i])
//                     (unique fixpoint == greedy NMS; iterate-until-stable is
//                     sound) + fused epilogue (argmax + masked writes).

constexpr int NROWS = 8192;
constexpr int NKW   = 256;                    // keep words (u32) per set
constexpr unsigned EDGE_CAP = 1536u * 1024u;  // per set; ~400x margin
#define IOU_T 0.6f

// ws layout (bytes):
//   [0,64)        cnt[2]
//   [64,...)      cellofs [2][257] u32
//   [4096,...)    sbox  [2][8192] float4 (sorted by cell)
//   [266240,...)  sarea [2][8192] float
//   [331776,...)  sidx  [2][8192] u32 (original row)
//   [397312,...)  edges [2][EDGE_CAP] u32
constexpr size_t OFF_CELLOFS = 64;
constexpr size_t OFF_SBOX    = 4096;
constexpr size_t OFF_SAREA   = OFF_SBOX  + 2ull * NROWS * 16;
constexpr size_t OFF_SIDX    = OFF_SAREA + 2ull * NROWS * 4;
constexpr size_t OFF_EDGES   = OFF_SIDX  + 2ull * NROWS * 4;

// ---------------------------------------------------------------------------
// Kernel 1: bin. grid = 2 blocks (one per set) x 1024 threads.
// Each thread owns 8 rows (strided). Cells: 128px, 16x16 grid over centers.
// ---------------------------------------------------------------------------
__global__ __launch_bounds__(1024) void bin_kernel(
    const float* __restrict__ det, const float* __restrict__ rpn,
    float4* __restrict__ sbox, float* __restrict__ sarea,
    unsigned* __restrict__ sidx, unsigned* __restrict__ cellofs,
    unsigned* __restrict__ cnt)
{
  const int set  = blockIdx.x;
  const float* src  = (set == 0) ? det : rpn;
  const int    strd = (set == 0) ? 9 : 6;
  float4*   sb = sbox + (size_t)set * NROWS;
  float*    sa = sarea + (size_t)set * NROWS;
  unsigned* si = sidx + (size_t)set * NROWS;
  unsigned* co = cellofs + set * 257;

  __shared__ unsigned hist[256], scn[256], offsx[256], curs[256];
  const int t = threadIdx.x;
  if (t < 256) hist[t] = 0u;
  __syncthreads();

  float4 bx[8]; int cell[8];
  #pragma unroll
  for (int k = 0; k < 8; ++k) {
    const int r = t + k * 1024;
    const float* p = src + (size_t)r * strd + 1;
    const float4 v = make_float4(p[0], p[1], p[2], p[3]);
    bx[k] = v;
    const float cx = 0.5f * (v.x + v.z), cy = 0.5f * (v.y + v.w);
    const int ccx = min(15, max(0, (int)(cx * (1.0f / 128.0f))));
    const int ccy = min(15, max(0, (int)(cy * (1.0f / 128.0f))));
    cell[k] = ccy * 16 + ccx;
    atomicAdd(&hist[cell[k]], 1u);
  }
  __syncthreads();

  // Hillis-Steele inclusive scan over 256 cells
  if (t < 256) scn[t] = hist[t];
  __syncthreads();
  for (int d = 1; d < 256; d <<= 1) {
    unsigned v = 0u;
    if (t < 256) { v = scn[t]; if (t >= d) v += scn[t - d]; }
    __syncthreads();
    if (t < 256) scn[t] = v;
    __syncthreads();
  }
  if (t < 256) {
    const unsigned ex = scn[t] - hist[t];
    offsx[t] = ex; curs[t] = 0u; co[t] = ex;
  }
  if (t == 0) { co[256] = (unsigned)NROWS; cnt[set] = 0u; }
  __syncthreads();

  #pragma unroll
  for (int k = 0; k < 8; ++k) {
    const int r = t + k * 1024;
    const unsigned pos = offsx[cell[k]] + atomicAdd(&curs[cell[k]], 1u);
    const float4 v = bx[k];
    sb[pos] = v;
    sa[pos] = fmaxf(v.z - v.x, 0.0f) * fmaxf(v.w - v.y, 0.0f);  // ref area expr
    si[pos] = (unsigned)r;
  }
}

// ---------------------------------------------------------------------------
// Kernel 2: pair tests. grid = (256 cells, 2 sets) x 256 threads.
// For each box a in the cell, threads stride over the 3x3-neighborhood boxes
// (3 contiguous runs in the cell-sorted array). Each unordered pair is tested
// from both sides; the side with orig_a < orig_b computes IOU and emits —
// exactly-once emission, symmetric fp ops so both sides agree bitwise.
// IOU expression is byte-identical to the reference (IEEE div, same order).
// ---------------------------------------------------------------------------
__global__ __launch_bounds__(256) void pair_kernel(
    const float4* __restrict__ sbox, const float* __restrict__ sarea,
    const unsigned* __restrict__ sidx, const unsigned* __restrict__ cellofs,
    unsigned* __restrict__ cnt, unsigned* __restrict__ edges)
{
  const int cellid = blockIdx.x, set = blockIdx.y;
  const float4*   sb = sbox + (size_t)set * NROWS;
  const float*    sa = sarea + (size_t)set * NROWS;
  const unsigned* si = sidx + (size_t)set * NROWS;
  const unsigned* co = cellofs + set * 257;
  unsigned* ebase = edges + (size_t)set * EDGE_CAP;

  const int cx = cellid & 15, cy = cellid >> 4;
  const unsigned a0 = co[cellid], a1 = co[cellid + 1];
  if (a0 == a1) return;

  unsigned runlo[3], runhi[3];
  int nr = 0;
  const int xlo = max(cx - 1, 0), xhi = min(cx + 1, 15);
  #pragma unroll
  for (int dy = -1; dy <= 1; ++dy) {
    const int yy = cy + dy;
    if (yy < 0 || yy > 15) continue;
    runlo[nr] = co[yy * 16 + xlo];
    runhi[nr] = co[yy * 16 + xhi + 1];
    ++nr;
  }

  const int t = threadIdx.x;
  for (unsigned a = a0; a < a1; ++a) {           // uniform -> scalar loads
    const float4  A  = sb[a];
    const float   aa = sa[a];
    const unsigned ia = si[a];
    for (int r = 0; r < nr; ++r) {
      for (unsigned b = runlo[r] + t; b < runhi[r]; b += 256) {
        const float4 B = sb[b];
        const float ix1 = fmaxf(A.x, B.x), iy1 = fmaxf(A.y, B.y);
        const float ix2 = fminf(A.z, B.z), iy2 = fminf(A.w, B.w);
        const float inter = fmaxf(ix2 - ix1, 0.0f) * fmaxf(iy2 - iy1, 0.0f);
        if (inter > 0.0f) {
          const unsigned ib = si[b];
          if (ia < ib) {                         // emit-once side (skips self)
            const float uni = aa + sa[b] - inter;          // ref order
            const float iou = inter / fmaxf(uni, 1e-9f);   // ref expr
            if (iou > IOU_T) {
              const unsigned idx = atomicAdd(&cnt[set], 1u);
              if (idx < EDGE_CAP) ebase[idx] = (ia << 13) | ib;
            }
          }
        }
      }
    }
  }
}

// ---------------------------------------------------------------------------
// Kernel 3: Jacobi fixpoint + fused epilogue. grid = 2 blocks x 1024.
// keep^{t+1}[j] = !(exists edge (i,j) with keep^t[i]); iterate until a round
// changes nothing => x == F(x) => unique fixpoint == greedy NMS (proof: after
// r rounds all depth<=r rows are final; a stable round pins the rest).
// Then block 0 writes out0/out1 (det + argmax), block 1 writes out2 (rpn).
// ---------------------------------------------------------------------------
__global__ __launch_bounds__(1024) void solve_kernel(
    const float* __restrict__ det, const float* __restrict__ rpn,
    const unsigned* __restrict__ cnt, const unsigned* __restrict__ edges,
    float* __restrict__ out)
{
  const int set = blockIdx.x;
  const unsigned E = min(cnt[set], EDGE_CAP);
  const unsigned* eds = edges + (size_t)set * EDGE_CAP;

  __shared__ unsigned kbuf[2][NKW];
  __shared__ int changed;

  const int t = threadIdx.x;
  if (t < NKW) kbuf[0][t] = 0xFFFFFFFFu;
  __syncthreads();

  int cur = 0;
  for (int round = 0; round < NROWS + 8; ++round) {
    const int nxt = cur ^ 1;
    if (t == 0) changed = 0;
    if (t < NKW) kbuf[nxt][t] = 0xFFFFFFFFu;
    __syncthreads();

    for (unsigned e = t; e < E; e += 1024) {
      const unsigned pk = eds[e];
      const unsigned i = pk >> 13, j = pk & 8191u;
      if ((kbuf[cur][i >> 5] >> (i & 31)) & 1u)
        atomicAnd(&kbuf[nxt][j >> 5], ~(1u << (j & 31)));
    }
    __syncthreads();

    if (t < NKW && kbuf[nxt][t] != kbuf[cur][t]) changed = 1;
    __syncthreads();

    cur = nxt;
    if (!changed) break;      // F(x)==x -> the unique fixpoint
  }

  if (set == 0) {
    for (int r = t; r < NROWS; r += 1024) {
      const bool kd = (kbuf[cur][r >> 5] >> (r & 31)) & 1u;
      const float* p = det + (size_t)r * 9;
      const float sc0 = p[5], sc1 = p[6], sc2 = p[7], sc3 = p[8];
      int am = 0; float best = sc0;
      if (sc1 > best) { best = sc1; am = 1; }   // first-max, like jnp.argmax
      if (sc2 > best) { best = sc2; am = 2; }
      if (sc3 > best) { best = sc3; am = 3; }
      const float vm = (kd && am != 0) ? 1.0f : 0.0f;
      const float im = (kd && am == 0) ? 1.0f : 0.0f;
      float* o0 = out + (size_t)r * 9;
      float* o1 = out + (size_t)NROWS * 9 + (size_t)r * 9;
      #pragma unroll
      for (int c = 0; c < 9; ++c) { const float v = p[c]; o0[c] = v * vm; o1[c] = v * im; }
    }
  } else {
    for (int r = t; r < NROWS; r += 1024) {
      const bool kr = (kbuf[cur][r >> 5] >> (r & 31)) & 1u;
      const float rm = kr ? 1.0f : 0.0f;
      const float* q = rpn + (size_t)r * 6;
      float* o2 = out + (size_t)NROWS * 18 + (size_t)r * 6;
      #pragma unroll
      for (int c = 0; c < 6; ++c) o2[c] = q[c] * rm;
    }
  }
}

// ---------------------------------------------------------------------------
extern "C" void kernel_launch(void* const* d_in, const int* in_sizes, int n_in,
                              void* d_out, int out_size, void* d_ws, size_t ws_size,
                              hipStream_t stream)
{
  const float* det = (const float*)d_in[0];   // 8192 x 9 fp32
  const float* rpn = (const float*)d_in[1];   // 8192 x 6 fp32
  float* out = (float*)d_out;                 // 8192*9 + 8192*9 + 8192*6 fp32

  char* ws = (char*)d_ws;
  unsigned* cnt     = (unsigned*)ws;
  unsigned* cellofs = (unsigned*)(ws + OFF_CELLOFS);
  float4*   sbox    = (float4*)  (ws + OFF_SBOX);
  float*    sarea   = (float*)   (ws + OFF_SAREA);
  unsigned* sidx    = (unsigned*)(ws + OFF_SIDX);
  unsigned* edges   = (unsigned*)(ws + OFF_EDGES);

  bin_kernel<<<2, 1024, 0, stream>>>(det, rpn, sbox, sarea, sidx, cellofs, cnt);
  dim3 g2(256, 2);
  pair_kernel<<<g2, 256, 0, stream>>>(sbox, sarea, sidx, cellofs, cnt, edges);
  solve_kernel<<<2, 1024, 0, stream>>>(det, rpn, cnt, edges, out);
}

// Round 8
// 118.993 us; speedup vs baseline: 1.2062x; 1.2062x over previous
//
#include <hip/hip_runtime.h>

// Pipeline_8400956031319: dual greedy NMS (8192 det + 8192 rpn, IOU>0.6,
// index order) + argmax masking.
//
// Binned sparse pipeline (R7 rev):
//   K1 bin:   per set, bin boxes by center into 16x16 grid of 128px cells
//             (box size <=120 < 128 => only 3x3 neighborhoods can overlap);
//             LDS histogram + wave0 shuffle-scan (2 barriers, not 16),
//             scatter cell-sorted box/area/idx; zero edge counters.
//   K2 pair:  per (cell,set): stage 3x3 neighborhood + cell boxes into LDS
//             (coalesced), then all pair tests LDS-resident (R7's version
//             was a serial global-latency chain per cell box -> 56us).
//             Exact ref IOU on inter>0 pairs; emit (i<<13|j) once (i<j).
//   K3 solve: Jacobi fixpoint keep[j] = !(exists i<j edge with keep[i]) —
//             unique fixpoint == greedy NMS; iterate until stable (sound).
//             Edges cached in LDS; parity 'changed' flags (no race).
//   K4 epi:   32-block epilogue: argmax + masked writes (wide stores spread
//             across CUs, not 2).

constexpr int NROWS = 8192;
constexpr int NKW   = 256;                    // keep words (u32) per set
constexpr unsigned EDGE_CAP = 1536u * 1024u;  // per set; huge margin
constexpr unsigned ELDS     = 16384u;         // edges cached in LDS (64 KB)
#define IOU_T 0.6f

// ws layout (bytes):
constexpr size_t OFF_CELLOFS = 64;                            // [2][257] u32
constexpr size_t OFF_SBOX    = 4096;                          // [2][8192] float4
constexpr size_t OFF_SAREA   = OFF_SBOX  + 2ull * NROWS * 16; // [2][8192] f32
constexpr size_t OFF_SIDX    = OFF_SAREA + 2ull * NROWS * 4;  // [2][8192] u32
constexpr size_t OFF_KEEP    = OFF_SIDX  + 2ull * NROWS * 4;  // [2][256] u32
constexpr size_t OFF_EDGES   = OFF_KEEP  + 2048;              // [2][CAP] u32

// ---------------------------------------------------------------------------
// K1: bin. grid = 2 blocks (one per set) x 1024 threads, 8 rows/thread.
// ---------------------------------------------------------------------------
__global__ __launch_bounds__(1024) void bin_kernel(
    const float* __restrict__ det, const float* __restrict__ rpn,
    float4* __restrict__ sbox, float* __restrict__ sarea,
    unsigned* __restrict__ sidx, unsigned* __restrict__ cellofs,
    unsigned* __restrict__ cnt)
{
  const int set  = blockIdx.x;
  const float* src  = (set == 0) ? det : rpn;
  const int    strd = (set == 0) ? 9 : 6;
  float4*   sb = sbox + (size_t)set * NROWS;
  float*    sa = sarea + (size_t)set * NROWS;
  unsigned* si = sidx + (size_t)set * NROWS;
  unsigned* co = cellofs + set * 257;

  __shared__ unsigned hist[256], offsx[256], curs[256];
  const int t = threadIdx.x;
  if (t < 256) hist[t] = 0u;
  __syncthreads();

  float4 bx[8]; int cell[8];
  #pragma unroll
  for (int k = 0; k < 8; ++k) {
    const int r = t + k * 1024;
    const float* p = src + (size_t)r * strd + 1;
    const float4 v = make_float4(p[0], p[1], p[2], p[3]);
    bx[k] = v;
    const float cx = 0.5f * (v.x + v.z), cy = 0.5f * (v.y + v.w);
    const int ccx = min(15, max(0, (int)(cx * (1.0f / 128.0f))));
    const int ccy = min(15, max(0, (int)(cy * (1.0f / 128.0f))));
    cell[k] = ccy * 16 + ccx;
    atomicAdd(&hist[cell[k]], 1u);
  }
  __syncthreads();

  // wave0 shuffle-scan over 256 cells (4 cells/lane), no barriers inside
  if (t < 64) {
    const unsigned h0 = hist[4 * t], h1 = hist[4 * t + 1];
    const unsigned h2 = hist[4 * t + 2], h3 = hist[4 * t + 3];
    const unsigned lsum = h0 + h1 + h2 + h3;
    unsigned incl = lsum;
    #pragma unroll
    for (int d = 1; d < 64; d <<= 1) {
      const unsigned v = __shfl_up(incl, d);
      if (t >= d) incl += v;
    }
    unsigned base = incl - lsum;                  // exclusive over lanes
    const unsigned o0 = base, o1 = base + h0, o2 = o1 + h1, o3 = o2 + h2;
    offsx[4 * t] = o0; offsx[4 * t + 1] = o1;
    offsx[4 * t + 2] = o2; offsx[4 * t + 3] = o3;
    curs[4 * t] = 0u; curs[4 * t + 1] = 0u;
    curs[4 * t + 2] = 0u; curs[4 * t + 3] = 0u;
    co[4 * t] = o0; co[4 * t + 1] = o1; co[4 * t + 2] = o2; co[4 * t + 3] = o3;
  }
  if (t == 0) { co[256] = (unsigned)NROWS; cnt[set] = 0u; }
  __syncthreads();

  #pragma unroll
  for (int k = 0; k < 8; ++k) {
    const int r = t + k * 1024;
    const unsigned pos = offsx[cell[k]] + atomicAdd(&curs[cell[k]], 1u);
    const float4 v = bx[k];
    sb[pos] = v;
    sa[pos] = fmaxf(v.z - v.x, 0.0f) * fmaxf(v.w - v.y, 0.0f);  // ref area expr
    si[pos] = (unsigned)r;
  }
}

// ---------------------------------------------------------------------------
// K2: pair tests, LDS-staged. grid = (256 cells, 2 sets) x 256 threads.
// Neighborhood (3 contiguous runs) staged into LDS in 1024-box chunks,
// cell boxes in 128-box chunks; all pair tests then read LDS only.
// Emit iff orig_a < orig_b (exactly-once; skips self). IOU expression is
// byte-identical to the reference (IEEE div, same operand order: union =
// area[i] + area[j] - inter with i the smaller original index).
// ---------------------------------------------------------------------------
__global__ __launch_bounds__(256) void pair_kernel(
    const float4* __restrict__ sbox, const float* __restrict__ sarea,
    const unsigned* __restrict__ sidx, const unsigned* __restrict__ cellofs,
    unsigned* __restrict__ cnt, unsigned* __restrict__ edges)
{
  const int cellid = blockIdx.x, set = blockIdx.y;
  const float4*   sb = sbox + (size_t)set * NROWS;
  const float*    sa = sarea + (size_t)set * NROWS;
  const unsigned* si = sidx + (size_t)set * NROWS;
  const unsigned* co = cellofs + set * 257;
  unsigned* ebase = edges + (size_t)set * EDGE_CAP;

  const int cx = cellid & 15, cy = cellid >> 4;
  const unsigned a0 = co[cellid], a1 = co[cellid + 1];
  if (a0 == a1) return;

  unsigned runlo[3], runhi[3];
  int nr = 0;
  const int xlo = max(cx - 1, 0), xhi = min(cx + 1, 15);
  #pragma unroll
  for (int dy = -1; dy <= 1; ++dy) {
    const int yy = cy + dy;
    if (yy < 0 || yy > 15) continue;
    runlo[nr] = co[yy * 16 + xlo];
    runhi[nr] = co[yy * 16 + xhi + 1];
    ++nr;
  }

  __shared__ float4   Bb[1024];
  __shared__ float    Ba[1024];
  __shared__ unsigned Bi[1024];
  __shared__ float4   Ab[128];
  __shared__ float    Aa[128];
  __shared__ unsigned Ai[128];

  const int t = threadIdx.x;

  for (unsigned ac = a0; ac < a1; ac += 128) {          // uniform bounds
    const unsigned na = min(a1 - ac, 128u);
    __syncthreads();                                    // protect Ab reuse
    if (t < (int)na) {
      Ab[t] = sb[ac + t]; Aa[t] = sa[ac + t]; Ai[t] = si[ac + t];
    }
    for (int r = 0; r < nr; ++r) {
      for (unsigned bc = runlo[r]; bc < runhi[r]; bc += 1024) {
        const unsigned nb = min(runhi[r] - bc, 1024u);
        __syncthreads();                                // protect Bb reuse
        for (unsigned x = t; x < nb; x += 256) {
          Bb[x] = sb[bc + x]; Ba[x] = sa[bc + x]; Bi[x] = si[bc + x];
        }
        __syncthreads();
        for (unsigned ai = 0; ai < na; ++ai) {          // uniform; LDS bcast
          const float4   A  = Ab[ai];
          const float    aa = Aa[ai];
          const unsigned ia = Ai[ai];
          for (unsigned x = t; x < nb; x += 256) {
            const float4 B = Bb[x];
            const float ix1 = fmaxf(A.x, B.x), iy1 = fmaxf(A.y, B.y);
            const float ix2 = fminf(A.z, B.z), iy2 = fminf(A.w, B.w);
            const float inter = fmaxf(ix2 - ix1, 0.0f) * fmaxf(iy2 - iy1, 0.0f);
            if (inter > 0.0f) {
              const unsigned ib = Bi[x];
              if (ia < ib) {                            // emit-once (skips self)
                const float uni = aa + Ba[x] - inter;         // ref order
                const float iou = inter / fmaxf(uni, 1e-9f);  // ref expr
                if (iou > IOU_T) {
                  const unsigned idx = atomicAdd(&cnt[set], 1u);
                  if (idx < EDGE_CAP) ebase[idx] = (ia << 13) | ib;
                }
              }
            }
          }
        }
      }
    }
  }
}

// ---------------------------------------------------------------------------
// K3: Jacobi fixpoint. grid = 2 blocks x 1024.
// keep^{t+1}[j] = !(exists edge (i,j), keep^t[i]); stable round => unique
// fixpoint == greedy NMS (induction on suppression depth). Edges cached in
// LDS (global fallback past ELDS). 'changed' is parity-buffered: slot b&1 is
// reset at round b, read after round b's last barrier; its next reset (round
// b+2) is ordered after round b+1's barriers => no read/write race.
// ---------------------------------------------------------------------------
__global__ __launch_bounds__(1024) void solve_kernel(
    const unsigned* __restrict__ cnt, const unsigned* __restrict__ edges,
    unsigned* __restrict__ keep)
{
  const int set = blockIdx.x;
  const unsigned E = min(cnt[set], EDGE_CAP);
  const unsigned* eds = edges + (size_t)set * EDGE_CAP;
  unsigned* kout = keep + set * NKW;

  __shared__ unsigned eL[ELDS];
  __shared__ unsigned kbuf[2][NKW];
  __shared__ int changed[2];

  const int t = threadIdx.x;
  const unsigned EL = min(E, ELDS);
  for (unsigned e = t; e < EL; e += 1024) eL[e] = eds[e];
  if (t < NKW) kbuf[0][t] = 0xFFFFFFFFu;
  // (first __syncthreads below covers eL/kbuf staging)

  int cur = 0;
  for (int round = 0; round < NROWS + 8; ++round) {
    const int nxt = cur ^ 1;
    if (t == 0) changed[round & 1] = 0;
    if (t < NKW) kbuf[nxt][t] = 0xFFFFFFFFu;
    __syncthreads();

    for (unsigned e = t; e < E; e += 1024) {
      const unsigned pk = (e < ELDS) ? eL[e] : eds[e];
      const unsigned i = pk >> 13, j = pk & 8191u;
      if ((kbuf[cur][i >> 5] >> (i & 31)) & 1u)
        atomicAnd(&kbuf[nxt][j >> 5], ~(1u << (j & 31)));
    }
    __syncthreads();

    if (t < NKW && kbuf[nxt][t] != kbuf[cur][t]) changed[round & 1] = 1;
    __syncthreads();

    cur = nxt;
    if (!changed[round & 1]) break;   // F(x)==x -> the unique fixpoint
  }

  if (t < NKW) kout[t] = kbuf[cur][t];
}

// ---------------------------------------------------------------------------
// K4: epilogue. 32 blocks x 256: argmax (first-max, like jnp.argmax) + keep
// bits -> three masked outputs.
// ---------------------------------------------------------------------------
__global__ __launch_bounds__(256) void epilogue_kernel(
    const float* __restrict__ det, const float* __restrict__ rpn,
    const unsigned* __restrict__ keep, float* __restrict__ out)
{
  const int i = blockIdx.x * 256 + threadIdx.x;
  if (i >= NROWS) return;
  const bool kd = (keep[i >> 5]         >> (i & 31)) & 1u;
  const bool kr = (keep[NKW + (i >> 5)] >> (i & 31)) & 1u;

  const float* p = det + (size_t)i * 9;
  const float sc0 = p[5], sc1 = p[6], sc2 = p[7], sc3 = p[8];
  int am = 0; float best = sc0;
  if (sc1 > best) { best = sc1; am = 1; }
  if (sc2 > best) { best = sc2; am = 2; }
  if (sc3 > best) { best = sc3; am = 3; }

  const float vm = (kd && am != 0) ? 1.0f : 0.0f;
  const float im = (kd && am == 0) ? 1.0f : 0.0f;
  float* o0 = out + (size_t)i * 9;
  float* o1 = out + (size_t)NROWS * 9 + (size_t)i * 9;
  #pragma unroll
  for (int c = 0; c < 9; ++c) { const float v = p[c]; o0[c] = v * vm; o1[c] = v * im; }

  const float rm = kr ? 1.0f : 0.0f;
  const float* q = rpn + (size_t)i * 6;
  float* o2 = out + (size_t)NROWS * 18 + (size_t)i * 6;
  #pragma unroll
  for (int c = 0; c < 6; ++c) o2[c] = q[c] * rm;
}

// ---------------------------------------------------------------------------
extern "C" void kernel_launch(void* const* d_in, const int* in_sizes, int n_in,
                              void* d_out, int out_size, void* d_ws, size_t ws_size,
                              hipStream_t stream)
{
  const float* det = (const float*)d_in[0];   // 8192 x 9 fp32
  const float* rpn = (const float*)d_in[1];   // 8192 x 6 fp32
  float* out = (float*)d_out;                 // 8192*9 + 8192*9 + 8192*6 fp32

  char* ws = (char*)d_ws;
  unsigned* cnt     = (unsigned*)ws;
  unsigned* cellofs = (unsigned*)(ws + OFF_CELLOFS);
  float4*   sbox    = (float4*)  (ws + OFF_SBOX);
  float*    sarea   = (float*)   (ws + OFF_SAREA);
  unsigned* sidx    = (unsigned*)(ws + OFF_SIDX);
  unsigned* keep    = (unsigned*)(ws + OFF_KEEP);
  unsigned* edges   = (unsigned*)(ws + OFF_EDGES);

  bin_kernel<<<2, 1024, 0, stream>>>(det, rpn, sbox, sarea, sidx, cellofs, cnt);
  dim3 g2(256, 2);
  pair_kernel<<<g2, 256, 0, stream>>>(sbox, sarea, sidx, cellofs, cnt, edges);
  solve_kernel<<<2, 1024, 0, stream>>>(cnt, edges, keep);
  epilogue_kernel<<<32, 256, 0, stream>>>(det, rpn, keep, out);
}

// Round 9
// 116.965 us; speedup vs baseline: 1.2271x; 1.0173x over previous
//
#include <hip/hip_runtime.h>

// Pipeline_8400956031319: dual greedy NMS (8192 det + 8192 rpn, IOU>0.6,
// index order) + argmax masking.
//
// Binned sparse pipeline (R8 rev):
//   K1 bin:   per set, bin boxes by center into 16x16 grid of 128px cells
//             (box size <=120 < 128 => only 3x3 neighborhoods overlap);
//             LDS histogram + wave0 shuffle-scan, scatter cell-sorted
//             box/area/idx; zero edge counters.
//   K2 pair:  per (cell,set): stage 3x3 neighborhood + cell boxes into LDS,
//             all pair tests LDS-resident. Edges buffered in LDS and flushed
//             with ONE global atomicAdd per block (R8 did ~6000 same-line
//             device atomics = ~42us serialized chain -> the whole 45us).
//             cnt[0]/cnt[1] padded 128B apart (no false sharing).
//   K3 solve: Jacobi fixpoint keep[j] = !(exists i<j edge with keep[i]) —
//             unique fixpoint == greedy NMS; iterate until stable (sound).
//   K4 epi:   32-block epilogue: argmax + masked writes.

constexpr int NROWS = 8192;
constexpr int NKW   = 256;                    // keep words (u32) per set
constexpr unsigned EDGE_CAP = 1536u * 1024u;  // per set; huge margin
constexpr unsigned ELDS     = 16384u;         // edges cached in LDS (solve)
constexpr unsigned EBUF     = 2048u;          // per-block LDS edge buffer
constexpr int CNT_STRIDE    = 32;             // u32s between cnt[0]/cnt[1] (128B)
#define IOU_T 0.6f

// ws layout (bytes):
constexpr size_t OFF_CELLOFS = 512;                           // [2][257] u32
constexpr size_t OFF_SBOX    = 4608;                          // [2][8192] float4
constexpr size_t OFF_SAREA   = OFF_SBOX  + 2ull * NROWS * 16; // [2][8192] f32
constexpr size_t OFF_SIDX    = OFF_SAREA + 2ull * NROWS * 4;  // [2][8192] u32
constexpr size_t OFF_KEEP    = OFF_SIDX  + 2ull * NROWS * 4;  // [2][256] u32
constexpr size_t OFF_EDGES   = OFF_KEEP  + 2048;              // [2][CAP] u32

// ---------------------------------------------------------------------------
// K1: bin. grid = 2 blocks (one per set) x 1024 threads, 8 rows/thread.
// ---------------------------------------------------------------------------
__global__ __launch_bounds__(1024) void bin_kernel(
    const float* __restrict__ det, const float* __restrict__ rpn,
    float4* __restrict__ sbox, float* __restrict__ sarea,
    unsigned* __restrict__ sidx, unsigned* __restrict__ cellofs,
    unsigned* __restrict__ cnt)
{
  const int set  = blockIdx.x;
  const float* src  = (set == 0) ? det : rpn;
  const int    strd = (set == 0) ? 9 : 6;
  float4*   sb = sbox + (size_t)set * NROWS;
  float*    sa = sarea + (size_t)set * NROWS;
  unsigned* si = sidx + (size_t)set * NROWS;
  unsigned* co = cellofs + set * 257;

  __shared__ unsigned hist[256], offsx[256], curs[256];
  const int t = threadIdx.x;
  if (t < 256) hist[t] = 0u;
  __syncthreads();

  float4 bx[8]; int cell[8];
  #pragma unroll
  for (int k = 0; k < 8; ++k) {
    const int r = t + k * 1024;
    const float* p = src + (size_t)r * strd + 1;
    const float4 v = make_float4(p[0], p[1], p[2], p[3]);
    bx[k] = v;
    const float cx = 0.5f * (v.x + v.z), cy = 0.5f * (v.y + v.w);
    const int ccx = min(15, max(0, (int)(cx * (1.0f / 128.0f))));
    const int ccy = min(15, max(0, (int)(cy * (1.0f / 128.0f))));
    cell[k] = ccy * 16 + ccx;
    atomicAdd(&hist[cell[k]], 1u);
  }
  __syncthreads();

  // wave0 shuffle-scan over 256 cells (4 cells/lane)
  if (t < 64) {
    const unsigned h0 = hist[4 * t], h1 = hist[4 * t + 1];
    const unsigned h2 = hist[4 * t + 2], h3 = hist[4 * t + 3];
    const unsigned lsum = h0 + h1 + h2 + h3;
    unsigned incl = lsum;
    #pragma unroll
    for (int d = 1; d < 64; d <<= 1) {
      const unsigned v = __shfl_up(incl, d);
      if (t >= d) incl += v;
    }
    unsigned base = incl - lsum;                  // exclusive over lanes
    const unsigned o0 = base, o1 = base + h0, o2 = o1 + h1, o3 = o2 + h2;
    offsx[4 * t] = o0; offsx[4 * t + 1] = o1;
    offsx[4 * t + 2] = o2; offsx[4 * t + 3] = o3;
    curs[4 * t] = 0u; curs[4 * t + 1] = 0u;
    curs[4 * t + 2] = 0u; curs[4 * t + 3] = 0u;
    co[4 * t] = o0; co[4 * t + 1] = o1; co[4 * t + 2] = o2; co[4 * t + 3] = o3;
  }
  if (t == 0) { co[256] = (unsigned)NROWS; cnt[set * CNT_STRIDE] = 0u; }
  __syncthreads();

  #pragma unroll
  for (int k = 0; k < 8; ++k) {
    const int r = t + k * 1024;
    const unsigned pos = offsx[cell[k]] + atomicAdd(&curs[cell[k]], 1u);
    const float4 v = bx[k];
    sb[pos] = v;
    sa[pos] = fmaxf(v.z - v.x, 0.0f) * fmaxf(v.w - v.y, 0.0f);  // ref area expr
    si[pos] = (unsigned)r;
  }
}

// ---------------------------------------------------------------------------
// K2: pair tests, LDS-staged, LDS-batched edge emission.
// grid = (256 cells, 2 sets) x 256 threads.
// Emit iff orig_a < orig_b (exactly-once; skips self). IOU expression is
// byte-identical to the reference (IEEE div, same operand order: union =
// area[i] + area[j] - inter with i the smaller original index — both sides
// of a pair compute identical fp values since all ops are symmetric).
// Edge flush: one global atomicAdd per block (LDS slots via cheap LDS
// atomics); overflow beyond EBUF falls back to per-edge global atomics
// (never taken for this data — correctness-only path).
// ---------------------------------------------------------------------------
__global__ __launch_bounds__(256) void pair_kernel(
    const float4* __restrict__ sbox, const float* __restrict__ sarea,
    const unsigned* __restrict__ sidx, const unsigned* __restrict__ cellofs,
    unsigned* __restrict__ cnt, unsigned* __restrict__ edges)
{
  const int cellid = blockIdx.x, set = blockIdx.y;
  const float4*   sb = sbox + (size_t)set * NROWS;
  const float*    sa = sarea + (size_t)set * NROWS;
  const unsigned* si = sidx + (size_t)set * NROWS;
  const unsigned* co = cellofs + set * 257;
  unsigned* ebase = edges + (size_t)set * EDGE_CAP;
  unsigned* gcnt  = &cnt[set * CNT_STRIDE];

  const int cx = cellid & 15, cy = cellid >> 4;
  const unsigned a0 = co[cellid], a1 = co[cellid + 1];
  if (a0 == a1) return;

  unsigned runlo[3], runhi[3];
  int nr = 0;
  const int xlo = max(cx - 1, 0), xhi = min(cx + 1, 15);
  #pragma unroll
  for (int dy = -1; dy <= 1; ++dy) {
    const int yy = cy + dy;
    if (yy < 0 || yy > 15) continue;
    runlo[nr] = co[yy * 16 + xlo];
    runhi[nr] = co[yy * 16 + xhi + 1];
    ++nr;
  }

  __shared__ float4   Bb[1024];
  __shared__ float    Ba[1024];
  __shared__ unsigned Bi[1024];
  __shared__ float4   Ab[128];
  __shared__ float    Aa[128];
  __shared__ unsigned Ai[128];
  __shared__ unsigned eBuf[EBUF];
  __shared__ unsigned eCnt, eBase;

  const int t = threadIdx.x;
  if (t == 0) eCnt = 0u;

  for (unsigned ac = a0; ac < a1; ac += 128) {          // uniform bounds
    const unsigned na = min(a1 - ac, 128u);
    __syncthreads();                                    // covers eCnt init too
    if (t < (int)na) {
      Ab[t] = sb[ac + t]; Aa[t] = sa[ac + t]; Ai[t] = si[ac + t];
    }
    for (int r = 0; r < nr; ++r) {
      for (unsigned bc = runlo[r]; bc < runhi[r]; bc += 1024) {
        const unsigned nb = min(runhi[r] - bc, 1024u);
        __syncthreads();                                // protect Bb reuse
        for (unsigned x = t; x < nb; x += 256) {
          Bb[x] = sb[bc + x]; Ba[x] = sa[bc + x]; Bi[x] = si[bc + x];
        }
        __syncthreads();
        for (unsigned ai = 0; ai < na; ++ai) {          // uniform; LDS bcast
          const float4   A  = Ab[ai];
          const float    aa = Aa[ai];
          const unsigned ia = Ai[ai];
          for (unsigned x = t; x < nb; x += 256) {
            const float4 B = Bb[x];
            const float ix1 = fmaxf(A.x, B.x), iy1 = fmaxf(A.y, B.y);
            const float ix2 = fminf(A.z, B.z), iy2 = fminf(A.w, B.w);
            const float inter = fmaxf(ix2 - ix1, 0.0f) * fmaxf(iy2 - iy1, 0.0f);
            if (inter > 0.0f) {
              const unsigned ib = Bi[x];
              if (ia < ib) {                            // emit-once (skips self)
                const float uni = aa + Ba[x] - inter;         // ref order
                const float iou = inter / fmaxf(uni, 1e-9f);  // ref expr
                if (iou > IOU_T) {
                  const unsigned slot = atomicAdd(&eCnt, 1u); // LDS atomic
                  const unsigned pk = (ia << 13) | ib;
                  if (slot < EBUF) {
                    eBuf[slot] = pk;
                  } else {                              // overflow: slow exact
                    const unsigned gi = atomicAdd(gcnt, 1u);
                    if (gi < EDGE_CAP) ebase[gi] = pk;
                  }
                }
              }
            }
          }
        }
      }
    }
  }

  // flush: ONE global atomic per block, coalesced edge writes
  __syncthreads();
  const unsigned ne = min(eCnt, EBUF);
  if (t == 0 && ne > 0u) eBase = atomicAdd(gcnt, ne);
  __syncthreads();
  for (unsigned x = t; x < ne; x += 256) {
    const unsigned gi = eBase + x;
    if (gi < EDGE_CAP) ebase[gi] = eBuf[x];
  }
}

// ---------------------------------------------------------------------------
// K3: Jacobi fixpoint. grid = 2 blocks x 1024.
// keep^{t+1}[j] = !(exists edge (i,j), keep^t[i]); stable round => unique
// fixpoint == greedy NMS (induction on suppression depth). Edges cached in
// LDS (global fallback past ELDS). 'changed' parity-buffered (race-free).
// ---------------------------------------------------------------------------
__global__ __launch_bounds__(1024) void solve_kernel(
    const unsigned* __restrict__ cnt, const unsigned* __restrict__ edges,
    unsigned* __restrict__ keep)
{
  const int set = blockIdx.x;
  const unsigned E = min(cnt[set * CNT_STRIDE], EDGE_CAP);
  const unsigned* eds = edges + (size_t)set * EDGE_CAP;
  unsigned* kout = keep + set * NKW;

  __shared__ unsigned eL[ELDS];
  __shared__ unsigned kbuf[2][NKW];
  __shared__ int changed[2];

  const int t = threadIdx.x;
  const unsigned EL = min(E, ELDS);
  for (unsigned e = t; e < EL; e += 1024) eL[e] = eds[e];
  if (t < NKW) kbuf[0][t] = 0xFFFFFFFFu;
  // first __syncthreads below covers staging

  int cur = 0;
  for (int round = 0; round < NROWS + 8; ++round) {
    const int nxt = cur ^ 1;
    if (t == 0) changed[round & 1] = 0;
    if (t < NKW) kbuf[nxt][t] = 0xFFFFFFFFu;
    __syncthreads();

    for (unsigned e = t; e < E; e += 1024) {
      const unsigned pk = (e < ELDS) ? eL[e] : eds[e];
      const unsigned i = pk >> 13, j = pk & 8191u;
      if ((kbuf[cur][i >> 5] >> (i & 31)) & 1u)
        atomicAnd(&kbuf[nxt][j >> 5], ~(1u << (j & 31)));
    }
    __syncthreads();

    if (t < NKW && kbuf[nxt][t] != kbuf[cur][t]) changed[round & 1] = 1;
    __syncthreads();

    cur = nxt;
    if (!changed[round & 1]) break;   // F(x)==x -> the unique fixpoint
  }

  if (t < NKW) kout[t] = kbuf[cur][t];
}

// ---------------------------------------------------------------------------
// K4: epilogue. 32 blocks x 256: argmax (first-max, like jnp.argmax) + keep
// bits -> three masked outputs.
// ---------------------------------------------------------------------------
__global__ __launch_bounds__(256) void epilogue_kernel(
    const float* __restrict__ det, const float* __restrict__ rpn,
    const unsigned* __restrict__ keep, float* __restrict__ out)
{
  const int i = blockIdx.x * 256 + threadIdx.x;
  if (i >= NROWS) return;
  const bool kd = (keep[i >> 5]         >> (i & 31)) & 1u;
  const bool kr = (keep[NKW + (i >> 5)] >> (i & 31)) & 1u;

  const float* p = det + (size_t)i * 9;
  const float sc0 = p[5], sc1 = p[6], sc2 = p[7], sc3 = p[8];
  int am = 0; float best = sc0;
  if (sc1 > best) { best = sc1; am = 1; }
  if (sc2 > best) { best = sc2; am = 2; }
  if (sc3 > best) { best = sc3; am = 3; }

  const float vm = (kd && am != 0) ? 1.0f : 0.0f;
  const float im = (kd && am == 0) ? 1.0f : 0.0f;
  float* o0 = out + (size_t)i * 9;
  float* o1 = out + (size_t)NROWS * 9 + (size_t)i * 9;
  #pragma unroll
  for (int c = 0; c < 9; ++c) { const float v = p[c]; o0[c] = v * vm; o1[c] = v * im; }

  const float rm = kr ? 1.0f : 0.0f;
  const float* q = rpn + (size_t)i * 6;
  float* o2 = out + (size_t)NROWS * 18 + (size_t)i * 6;
  #pragma unroll
  for (int c = 0; c < 6; ++c) o2[c] = q[c] * rm;
}

// ---------------------------------------------------------------------------
extern "C" void kernel_launch(void* const* d_in, const int* in_sizes, int n_in,
                              void* d_out, int out_size, void* d_ws, size_t ws_size,
                              hipStream_t stream)
{
  const float* det = (const float*)d_in[0];   // 8192 x 9 fp32
  const float* rpn = (const float*)d_in[1];   // 8192 x 6 fp32
  float* out = (float*)d_out;                 // 8192*9 + 8192*9 + 8192*6 fp32

  char* ws = (char*)d_ws;
  unsigned* cnt     = (unsigned*)ws;                    // [2] u32, 128B apart
  unsigned* cellofs = (unsigned*)(ws + OFF_CELLOFS);
  float4*   sbox    = (float4*)  (ws + OFF_SBOX);
  float*    sarea   = (float*)   (ws + OFF_SAREA);
  unsigned* sidx    = (unsigned*)(ws + OFF_SIDX);
  unsigned* keep    = (unsigned*)(ws + OFF_KEEP);
  unsigned* edges   = (unsigned*)(ws + OFF_EDGES);

  bin_kernel<<<2, 1024, 0, stream>>>(det, rpn, sbox, sarea, sidx, cellofs, cnt);
  dim3 g2(256, 2);
  pair_kernel<<<g2, 256, 0, stream>>>(sbox, sarea, sidx, cellofs, cnt, edges);
  solve_kernel<<<2, 1024, 0, stream>>>(cnt, edges, keep);
  epilogue_kernel<<<32, 256, 0, stream>>>(det, rpn, keep, out);
}

// Round 10
// 88.669 us; speedup vs baseline: 1.6187x; 1.3191x over previous
//
#include <hip/hip_runtime.h>

// Pipeline_8400956031319: dual greedy NMS (8192 det + 8192 rpn, IOU>0.6,
// index order) + argmax masking.
//
// R9 rev — TWO dispatches (R9 had 4; ~13us/dispatch of gap on this harness,
// and the middle kernel pinned at ~44us across 3 structurally different
// versions => fixed-cost + serial-chain bound, not work bound):
//   K1 scanpair: one block per (cell,set) [16x16 grid of 128px cells; box
//        size <=120 < 128 => only 3x3 neighborhoods can overlap]. The block
//        scans the ENTIRE input (L2-resident, 492 KB) and stages its 3x3
//        neighborhood into LDS — no bin kernel, no dependency. Pair phase is
//        FLATTENED (p -> (a,b), ~36 independent tests/thread, no serial
//        per-a loop, no mid-phase barriers). Edges (i<<13|j, emitted once via
//        orig_a < orig_b) go to a PRIVATE per-block region — no global
//        atomics, no counter init. Exact IOU expression (IEEE div, ref op
//        order; fp add commutes bitwise so operand side is irrelevant).
//   K2 solve_epi: 32 blocks; blocks 0-15 (set 0) / 16-31 (set 1) each
//        redundantly gather ~3k edges to LDS and run the Jacobi fixpoint
//        keep[j] = !(exists i<j edge with keep[i]) (unique fixpoint ==
//        greedy NMS; iterate until stable), then write their 1/16 slice of
//        the outputs (argmax + masked copies).

constexpr int NROWS = 8192;
constexpr int NKW   = 256;      // keep words (u32) per set
constexpr unsigned BCAP = 1536; // staged neighborhood cap (mean ~288)
constexpr unsigned ACAP = 512;  // cell-member cap (mean ~32)
constexpr unsigned RCAP = 2048; // per-block edge region cap (mean ~12)
constexpr unsigned ELDS = 16384;// solve LDS edge cache
#define IOU_T 0.6f

// ws layout: cnts[2][256] u32 @ 0 ; edges[2*256][RCAP] u32 @ 4096
constexpr size_t OFF_EDGES = 4096;

// ---------------------------------------------------------------------------
// K1: fused scan + pair. grid = (256 cells, 2 sets) x 256 threads.
// ---------------------------------------------------------------------------
__global__ __launch_bounds__(256) void scanpair_kernel(
    const float* __restrict__ det, const float* __restrict__ rpn,
    unsigned* __restrict__ cnts, unsigned* __restrict__ edges)
{
  const int cellid = blockIdx.x, set = blockIdx.y;
  const float* src  = (set == 0) ? det : rpn;
  const int    strd = (set == 0) ? 9 : 6;
  unsigned* myedges = edges + ((size_t)(set * 256 + cellid)) * RCAP;
  const int cx = cellid & 15, cy = cellid >> 4;

  __shared__ float Bx1[BCAP], By1[BCAP], Bx2[BCAP], By2[BCAP], Bar[BCAP];
  __shared__ unsigned Bid[BCAP];
  __shared__ unsigned aList[ACAP];
  __shared__ unsigned bCnt, aCnt, eCnt, ovf;

  const int t = threadIdx.x;
  if (t == 0) { bCnt = 0u; aCnt = 0u; eCnt = 0u; ovf = 0u; }
  __syncthreads();

  // scan all rows; stage 3x3-neighborhood members into LDS
  for (int r = t; r < NROWS; r += 256) {
    const float* p = src + (size_t)r * strd + 1;
    const float x1 = p[0], y1 = p[1], x2 = p[2], y2 = p[3];
    const float cxe = 0.5f * (x1 + x2), cye = 0.5f * (y1 + y2);
    const int ccx = min(15, max(0, (int)(cxe * (1.0f / 128.0f))));
    const int ccy = min(15, max(0, (int)(cye * (1.0f / 128.0f))));
    const int dx = ccx - cx, dy = ccy - cy;
    if (dx >= -1 && dx <= 1 && dy >= -1 && dy <= 1) {
      const unsigned s = atomicAdd(&bCnt, 1u);
      if (s < BCAP) {
        Bx1[s] = x1; By1[s] = y1; Bx2[s] = x2; By2[s] = y2;
        Bar[s] = fmaxf(x2 - x1, 0.0f) * fmaxf(y2 - y1, 0.0f); // ref area expr
        Bid[s] = (unsigned)r;
        if (dx == 0 && dy == 0) {
          const unsigned as = atomicAdd(&aCnt, 1u);
          if (as < ACAP) aList[as] = s; else atomicOr(&ovf, 1u);
        }
      } else atomicOr(&ovf, 1u);
    }
  }
  __syncthreads();

  const unsigned nb = min(bCnt, BCAP);
  const unsigned na = min(aCnt, ACAP);

  if (!ovf) {
    // flattened pair phase: all tests independent, LDS-resident
    const unsigned tot = na * nb;
    for (unsigned p = t; p < tot; p += 256) {
      const unsigned ai = p / nb, x = p - ai * nb;
      const unsigned s = aList[ai];
      const unsigned ia = Bid[s], ib = Bid[x];
      if (ia < ib) {                                   // emit-once; skips self
        const float ix1 = fmaxf(Bx1[s], Bx1[x]), iy1 = fmaxf(By1[s], By1[x]);
        const float ix2 = fminf(Bx2[s], Bx2[x]), iy2 = fminf(By2[s], By2[x]);
        const float inter = fmaxf(ix2 - ix1, 0.0f) * fmaxf(iy2 - iy1, 0.0f);
        if (inter > 0.0f) {
          const float uni = Bar[s] + Bar[x] - inter;          // ref order
          const float iou = inter / fmaxf(uni, 1e-9f);        // ref expr
          if (iou > IOU_T) {
            const unsigned slot = atomicAdd(&eCnt, 1u);       // LDS atomic
            if (slot < RCAP) myedges[slot] = (ia << 13) | ib;
          }
        }
      }
    }
  } else {
    // exact fallback (never taken for this data): a = rows in this cell
    // (recomputed inline), b = ALL rows. Pairs outside the neighborhood have
    // inter==0 geometrically, so semantics are identical to the fast path.
    for (int ra = 0; ra < NROWS; ++ra) {
      const float* pa = src + (size_t)ra * strd + 1;
      const float ax1 = pa[0], ay1 = pa[1], ax2 = pa[2], ay2 = pa[3];
      const float cxe = 0.5f * (ax1 + ax2), cye = 0.5f * (ay1 + ay2);
      const int ccx = min(15, max(0, (int)(cxe * (1.0f / 128.0f))));
      const int ccy = min(15, max(0, (int)(cye * (1.0f / 128.0f))));
      if (ccx != cx || ccy != cy) continue;            // uniform skip
      const float aar = fmaxf(ax2 - ax1, 0.0f) * fmaxf(ay2 - ay1, 0.0f);
      for (int rb = t; rb < NROWS; rb += 256) {
        if ((unsigned)ra >= (unsigned)rb) continue;
        const float* pb = src + (size_t)rb * strd + 1;
        const float bx1 = pb[0], by1 = pb[1], bx2 = pb[2], by2 = pb[3];
        const float ix1 = fmaxf(ax1, bx1), iy1 = fmaxf(ay1, by1);
        const float ix2 = fminf(ax2, bx2), iy2 = fminf(ay2, by2);
        const float inter = fmaxf(ix2 - ix1, 0.0f) * fmaxf(iy2 - iy1, 0.0f);
        if (inter > 0.0f) {
          const float bar = fmaxf(bx2 - bx1, 0.0f) * fmaxf(by2 - by1, 0.0f);
          const float uni = aar + bar - inter;
          const float iou = inter / fmaxf(uni, 1e-9f);
          if (iou > IOU_T) {
            const unsigned slot = atomicAdd(&eCnt, 1u);
            if (slot < RCAP) myedges[slot] = ((unsigned)ra << 13) | (unsigned)rb;
          }
        }
      }
    }
  }
  __syncthreads();
  if (t == 0) cnts[set * 256 + cellid] = min(eCnt, RCAP);
}

// ---------------------------------------------------------------------------
// K2: fixpoint + epilogue. grid = 32 blocks x 1024. set = blk>>4; each block
// solves its set's fixpoint (redundantly, ~3k edges) then writes rows
// [slice*512, slice*512+512) of its outputs.
// ---------------------------------------------------------------------------
__global__ __launch_bounds__(1024) void solve_epi_kernel(
    const float* __restrict__ det, const float* __restrict__ rpn,
    const unsigned* __restrict__ cnts, const unsigned* __restrict__ edges,
    float* __restrict__ out)
{
  const int blk = blockIdx.x;
  const int set = blk >> 4;
  const int slice = blk & 15;
  const unsigned* gedges = edges + (size_t)set * 256 * RCAP;

  __shared__ unsigned eL[ELDS];
  __shared__ unsigned rcnt[256], roff[256];
  __shared__ unsigned kbuf[2][NKW];
  __shared__ int changed[2];
  __shared__ unsigned Etot_sh;

  const int t = threadIdx.x;
  if (t < 256) rcnt[t] = min(cnts[set * 256 + t], RCAP);
  __syncthreads();

  // wave0 shuffle-scan of 256 region counts (4/lane)
  if (t < 64) {
    const unsigned h0 = rcnt[4 * t], h1 = rcnt[4 * t + 1];
    const unsigned h2 = rcnt[4 * t + 2], h3 = rcnt[4 * t + 3];
    const unsigned lsum = h0 + h1 + h2 + h3;
    unsigned incl = lsum;
    #pragma unroll
    for (int d = 1; d < 64; d <<= 1) {
      const unsigned v = __shfl_up(incl, d);
      if (t >= d) incl += v;
    }
    const unsigned base = incl - lsum;
    roff[4 * t] = base;           roff[4 * t + 1] = base + h0;
    roff[4 * t + 2] = base + h0 + h1; roff[4 * t + 3] = base + h0 + h1 + h2;
    if (t == 63) Etot_sh = incl;
  }
  if (t < NKW) kbuf[0][t] = 0xFFFFFFFFu;
  __syncthreads();

  const unsigned Etot = Etot_sh;
  const bool cached = (Etot <= ELDS);
  if (cached && t < 256) {                 // gather region t's edges (~12)
    const unsigned c = rcnt[t], o = roff[t];
    for (unsigned k = 0; k < c; ++k) eL[o + k] = gedges[(size_t)t * RCAP + k];
  }
  __syncthreads();

  int cur = 0;
  for (int round = 0; round < NROWS + 8; ++round) {
    const int nxt = cur ^ 1;
    if (t == 0) changed[round & 1] = 0;
    if (t < NKW) kbuf[nxt][t] = 0xFFFFFFFFu;
    __syncthreads();

    if (cached) {
      for (unsigned e = t; e < Etot; e += 1024) {
        const unsigned pk = eL[e];
        const unsigned i = pk >> 13, j = pk & 8191u;
        if ((kbuf[cur][i >> 5] >> (i & 31)) & 1u)
          atomicAnd(&kbuf[nxt][j >> 5], ~(1u << (j & 31)));
      }
    } else {                                // exact slow path (never taken)
      for (unsigned r = (unsigned)t >> 2; r < 256u; r += 256u) {
        const unsigned c = rcnt[r];
        for (unsigned k = (unsigned)t & 3u; k < c; k += 4u) {
          const unsigned pk = gedges[(size_t)r * RCAP + k];
          const unsigned i = pk >> 13, j = pk & 8191u;
          if ((kbuf[cur][i >> 5] >> (i & 31)) & 1u)
            atomicAnd(&kbuf[nxt][j >> 5], ~(1u << (j & 31)));
        }
      }
    }
    __syncthreads();

    if (t < NKW && kbuf[nxt][t] != kbuf[cur][t]) changed[round & 1] = 1;
    __syncthreads();

    cur = nxt;
    if (!changed[round & 1]) break;  // F(x)==x -> the unique fixpoint
  }

  // epilogue slice: 512 rows per block
  const int r0 = slice * 512;
  if (set == 0) {
    for (int i = r0 + t; i < r0 + 512; i += 1024) {
      const bool kd = (kbuf[cur][i >> 5] >> (i & 31)) & 1u;
      const float* p = det + (size_t)i * 9;
      const float sc0 = p[5], sc1 = p[6], sc2 = p[7], sc3 = p[8];
      int am = 0; float best = sc0;
      if (sc1 > best) { best = sc1; am = 1; }   // first-max, like jnp.argmax
      if (sc2 > best) { best = sc2; am = 2; }
      if (sc3 > best) { best = sc3; am = 3; }
      const float vm = (kd && am != 0) ? 1.0f : 0.0f;
      const float im = (kd && am == 0) ? 1.0f : 0.0f;
      float* o0 = out + (size_t)i * 9;
      float* o1 = out + (size_t)NROWS * 9 + (size_t)i * 9;
      #pragma unroll
      for (int c = 0; c < 9; ++c) { const float v = p[c]; o0[c] = v * vm; o1[c] = v * im; }
    }
  } else {
    for (int i = r0 + t; i < r0 + 512; i += 1024) {
      const bool kr = (kbuf[cur][i >> 5] >> (i & 31)) & 1u;
      const float rm = kr ? 1.0f : 0.0f;
      const float* q = rpn + (size_t)i * 6;
      float* o2 = out + (size_t)NROWS * 18 + (size_t)i * 6;
      #pragma unroll
      for (int c = 0; c < 6; ++c) o2[c] = q[c] * rm;
    }
  }
}

// ---------------------------------------------------------------------------
extern "C" void kernel_launch(void* const* d_in, const int* in_sizes, int n_in,
                              void* d_out, int out_size, void* d_ws, size_t ws_size,
                              hipStream_t stream)
{
  const float* det = (const float*)d_in[0];   // 8192 x 9 fp32
  const float* rpn = (const float*)d_in[1];   // 8192 x 6 fp32
  float* out = (float*)d_out;                 // 8192*9 + 8192*9 + 8192*6 fp32

  char* ws = (char*)d_ws;
  unsigned* cnts  = (unsigned*)ws;            // [2][256] u32
  unsigned* edges = (unsigned*)(ws + OFF_EDGES);

  dim3 g1(256, 2);
  scanpair_kernel<<<g1, 256, 0, stream>>>(det, rpn, cnts, edges);
  solve_epi_kernel<<<32, 1024, 0, stream>>>(det, rpn, cnts, edges, out);
}